// Round 2
// baseline (3427.274 us; speedup 1.0000x reference)
//
#include <hip/hip_runtime.h>
#include <stdint.h>

typedef __attribute__((ext_vector_type(8))) short bf16x8;
typedef __attribute__((ext_vector_type(4))) float f32x4;
typedef __attribute__((ext_vector_type(4))) unsigned short u16x4;
typedef __attribute__((ext_vector_type(8))) unsigned short u16x8;
typedef unsigned int u32;
typedef unsigned short u16;

#define H_DIM 1024
#define V_DIM 32000
#define N_LAYER 8
#define N_BATCH 2
#define SEQ 2048
#define N_TOK 4096  // N_BATCH*SEQ

__device__ __forceinline__ u16 f2b(float f) {
  u32 u = __builtin_bit_cast(u32, f);
  return (u16)((u + 0x7fffu + ((u >> 16) & 1u)) >> 16);  // RNE
}
__device__ __forceinline__ float b2f(u16 h) {
  u32 u = ((u32)h) << 16;
  return __builtin_bit_cast(float, u);
}

// ---------------------------------------------------------------------------
// GEMM: C[M,N] = A[M,K] @ B[N,K]^T   (both operands bf16 row-major, K-contig)
// 128x128 tile, BK=64, 4 waves (2x2 of 64x64), mfma_f32_16x16x32_bf16.
// LDS: linear dest for global_load_lds; XOR swizzle (slot ^= row&7) applied to
// the per-lane GLOBAL source and to the ds_read address (both-sides, rule 21).
// ---------------------------------------------------------------------------
enum { EPI_BF16 = 0, EPI_RELU = 1, EPI_F32S = 2, EPI_RES = 3 };

template <int EPI>
__global__ __launch_bounds__(256) void gemm_nt(
    const u16* __restrict__ A, long sAz, int lda,
    const u16* __restrict__ B, long sBz, int ldb,
    const float* __restrict__ bias, float scale,
    float* __restrict__ Cf, long sCfz,
    u16* __restrict__ Cb, long sCbz,
    int ldc, int K)
{
  __shared__ char lds[32768];  // A tile 16KB + B tile 16KB, single-buffered
  char* ldsA = lds;
  char* ldsB = lds + 16384;

  const int tid = threadIdx.x;
  const int z = blockIdx.z;
  A += (size_t)z * sAz;
  B += (size_t)z * sBz;
  if constexpr (EPI == EPI_F32S || EPI == EPI_RES) Cf += (size_t)z * sCfz;
  if constexpr (EPI != EPI_F32S) Cb += (size_t)z * sCbz;

  const int m0 = blockIdx.x << 7;
  const int n0 = blockIdx.y << 7;
  const int wid = tid >> 6, ln = tid & 63;
  const int wm = wid >> 1, wn = wid & 1;
  const int hi = ln >> 4, fr = ln & 15;
  const int st_row = tid >> 3;   // 0..31 (row within 32-row chunk)
  const int st_slot = tid & 7;   // 16B slot within 128B row

  f32x4 acc[4][4];
#pragma unroll
  for (int m = 0; m < 4; ++m)
#pragma unroll
    for (int n = 0; n < 4; ++n) acc[m][n] = f32x4{0.f, 0.f, 0.f, 0.f};

  const int nK = K >> 6;
  for (int kt = 0; kt < nK; ++kt) {
    const int k0 = kt << 6;
    __syncthreads();  // previous tile's reads complete before overwrite
#pragma unroll
    for (int i = 0; i < 4; ++i) {
      const int row = (i << 5) + st_row;
      const int slot = st_slot ^ (row & 7);            // inverse swizzle on SOURCE
      const u16* g = A + (size_t)(m0 + row) * lda + (k0 + (slot << 3));
      __builtin_amdgcn_global_load_lds(
          (const __attribute__((address_space(1))) u32*)g,
          (__attribute__((address_space(3))) u32*)(ldsA + (i << 12) + (tid << 4)),
          16, 0, 0);
    }
#pragma unroll
    for (int i = 0; i < 4; ++i) {
      const int row = (i << 5) + st_row;
      const int slot = st_slot ^ (row & 7);
      const u16* g = B + (size_t)(n0 + row) * ldb + (k0 + (slot << 3));
      __builtin_amdgcn_global_load_lds(
          (const __attribute__((address_space(1))) u32*)g,
          (__attribute__((address_space(3))) u32*)(ldsB + (i << 12) + (tid << 4)),
          16, 0, 0);
    }
    __syncthreads();  // compiler drains vmcnt before s_barrier
#pragma unroll
    for (int kk = 0; kk < 2; ++kk) {
      bf16x8 af[4], bg[4];
#pragma unroll
      for (int m = 0; m < 4; ++m) {
        const int row = (wm << 6) + (m << 4) + fr;
        const int slot = ((kk << 2) + hi) ^ (row & 7);  // swizzled READ
        af[m] = *(const bf16x8*)(ldsA + (row << 7) + (slot << 4));
      }
#pragma unroll
      for (int n = 0; n < 4; ++n) {
        const int row = (wn << 6) + (n << 4) + fr;
        const int slot = ((kk << 2) + hi) ^ (row & 7);
        bg[n] = *(const bf16x8*)(ldsB + (row << 7) + (slot << 4));
      }
#pragma unroll
      for (int m = 0; m < 4; ++m)
#pragma unroll
        for (int n = 0; n < 4; ++n)
          acc[m][n] = __builtin_amdgcn_mfma_f32_16x16x32_bf16(af[m], bg[n], acc[m][n], 0, 0, 0);
    }
  }

  // Epilogue. C/D layout (verified m89/m91): col = ln&15, row = (ln>>4)*4 + i.
  const int crow0 = m0 + (wm << 6) + (hi << 2);
  const int ccol0 = n0 + (wn << 6) + fr;
  float bv[4] = {0.f, 0.f, 0.f, 0.f};
  if constexpr (EPI == EPI_BF16 || EPI == EPI_RELU || EPI == EPI_RES) {
    if (bias) {
#pragma unroll
      for (int n = 0; n < 4; ++n) bv[n] = bias[ccol0 + (n << 4)];
    }
  }
#pragma unroll
  for (int m = 0; m < 4; ++m) {
#pragma unroll
    for (int i = 0; i < 4; ++i) {
      const size_t row = (size_t)(crow0 + (m << 4) + i);
#pragma unroll
      for (int n = 0; n < 4; ++n) {
        const size_t idx = row * (size_t)ldc + (size_t)(ccol0 + (n << 4));
        const float v = acc[m][n][i];
        if constexpr (EPI == EPI_BF16) {
          Cb[idx] = f2b(v + bv[n]);
        } else if constexpr (EPI == EPI_RELU) {
          Cb[idx] = f2b(fmaxf(v + bv[n], 0.f));
        } else if constexpr (EPI == EPI_F32S) {
          Cf[idx] = v * scale;
        } else {  // EPI_RES: residual accumulate in f32 + dual write
          const float nv = Cf[idx] + v + bv[n];
          Cf[idx] = nv;
          Cb[idx] = f2b(nv);
        }
      }
    }
  }
}

// ---------------------------------------------------------------------------
// Transpose + convert to bf16: out[c][r] = bf16(in[r][c]).  64x64 LDS tiles.
// ---------------------------------------------------------------------------
template <typename TIN>
__global__ __launch_bounds__(256) void transpose_to_bf16(
    const TIN* __restrict__ in, long sInz, int ldin,
    u16* __restrict__ out, long sOutz, int ldout)
{
  __shared__ float tile[64][65];
  in += (size_t)blockIdx.z * sInz;
  out += (size_t)blockIdx.z * sOutz;
  const int r0 = blockIdx.x << 6;
  const int c0 = blockIdx.y << 6;
  const int t = threadIdx.x;
  const int ci = t & 63, ri = t >> 6;
#pragma unroll
  for (int i = 0; i < 16; ++i) {
    const TIN e = in[(size_t)(r0 + ri + (i << 2)) * ldin + (c0 + ci)];
    float v;
    if constexpr (sizeof(TIN) == 4) v = (float)e; else v = b2f((u16)e);
    tile[ri + (i << 2)][ci] = v;
  }
  __syncthreads();
  const int ro = t & 63, co = t >> 6;
#pragma unroll
  for (int i = 0; i < 16; ++i) {
    out[(size_t)(c0 + co + (i << 2)) * ldout + (r0 + ro)] = f2b(tile[ro][co + (i << 2)]);
  }
}

// ---------------------------------------------------------------------------
__global__ __launch_bounds__(256) void cvt_f32_bf16(
    const float* __restrict__ in, u16* __restrict__ out, long n)
{
  const long i = ((long)blockIdx.x * 256 + threadIdx.x) * 8;
  if (i + 8 > n) return;
  f32x4 a = *(const f32x4*)(in + i);
  f32x4 b = *(const f32x4*)(in + i + 4);
  u16x8 o;
#pragma unroll
  for (int j = 0; j < 4; ++j) { o[j] = f2b(a[j]); o[4 + j] = f2b(b[j]); }
  *(u16x8*)(out + i) = o;
}

__global__ __launch_bounds__(256) void embed_gather(
    const int* __restrict__ x, const float* __restrict__ E,
    float* __restrict__ Hf, u16* __restrict__ Hb)
{
  const size_t row = blockIdx.x;
  const int tok = x[row];
  const int t = threadIdx.x;
  f32x4 v = *(const f32x4*)(E + (size_t)tok * H_DIM + (t << 2));
  *(f32x4*)(Hf + row * H_DIM + (t << 2)) = v;
  u16x4 o;
#pragma unroll
  for (int j = 0; j < 4; ++j) o[j] = f2b(v[j]);
  *(u16x4*)(Hb + row * H_DIM + (t << 2)) = o;
}

__global__ __launch_bounds__(256) void softmax_rows(
    const float* __restrict__ S, u16* __restrict__ P)
{
  const size_t row = blockIdx.x;
  const float* sp = S + row * SEQ;
  const int t = threadIdx.x;
  f32x4 v0 = *(const f32x4*)(sp + (t << 3));
  f32x4 v1 = *(const f32x4*)(sp + (t << 3) + 4);
  float mx = fmaxf(fmaxf(fmaxf(v0[0], v0[1]), fmaxf(v0[2], v0[3])),
                   fmaxf(fmaxf(v1[0], v1[1]), fmaxf(v1[2], v1[3])));
  __shared__ float r1[4], r2[4];
  for (int off = 32; off; off >>= 1) mx = fmaxf(mx, __shfl_xor(mx, off, 64));
  if ((t & 63) == 0) r1[t >> 6] = mx;
  __syncthreads();
  mx = fmaxf(fmaxf(r1[0], r1[1]), fmaxf(r1[2], r1[3]));
  float e[8], s = 0.f;
#pragma unroll
  for (int i = 0; i < 4; ++i) { e[i] = __expf(v0[i] - mx); s += e[i]; }
#pragma unroll
  for (int i = 0; i < 4; ++i) { e[4 + i] = __expf(v1[i] - mx); s += e[4 + i]; }
  for (int off = 32; off; off >>= 1) s += __shfl_xor(s, off, 64);
  if ((t & 63) == 0) r2[t >> 6] = s;
  __syncthreads();
  s = r2[0] + r2[1] + r2[2] + r2[3];
  const float inv = 1.f / s;
  u16x8 o;
#pragma unroll
  for (int i = 0; i < 8; ++i) o[i] = f2b(e[i] * inv);
  *(u16x8*)(P + row * SEQ + (t << 3)) = o;
}

__global__ __launch_bounds__(256) void layernorm_rows(
    const float* __restrict__ Hp, const float* __restrict__ gamma,
    const float* __restrict__ beta, u16* __restrict__ O)
{
  const size_t row = blockIdx.x;
  const float* hp = Hp + row * H_DIM;
  const int t = threadIdx.x;
  f32x4 v = *(const f32x4*)(hp + (t << 2));
  float s = v[0] + v[1] + v[2] + v[3];
  __shared__ float r1[4], r2[4];
  for (int off = 32; off; off >>= 1) s += __shfl_xor(s, off, 64);
  if ((t & 63) == 0) r1[t >> 6] = s;
  __syncthreads();
  const float mu = (r1[0] + r1[1] + r1[2] + r1[3]) * (1.f / H_DIM);
  float sq = 0.f;
#pragma unroll
  for (int i = 0; i < 4; ++i) { const float d = v[i] - mu; sq += d * d; }
  for (int off = 32; off; off >>= 1) sq += __shfl_xor(sq, off, 64);
  if ((t & 63) == 0) r2[t >> 6] = sq;
  __syncthreads();
  const float var = (r2[0] + r2[1] + r2[2] + r2[3]) * (1.f / H_DIM);
  const float rs = rsqrtf(var + 1e-5f);
  f32x4 g = *(const f32x4*)(gamma + (t << 2));
  f32x4 b = *(const f32x4*)(beta + (t << 2));
  u16x4 o;
#pragma unroll
  for (int i = 0; i < 4; ++i) o[i] = f2b((v[i] - mu) * rs * g[i] + b[i]);
  *(u16x4*)(O + row * H_DIM + (t << 2)) = o;
}

// ---------------------------------------------------------------------------
extern "C" void kernel_launch(void* const* d_in, const int* in_sizes, int n_in,
                              void* d_out, int out_size, void* d_ws, size_t ws_size,
                              hipStream_t stream)
{
  const int* x        = (const int*)d_in[0];
  const float* embed  = (const float*)d_in[1];
  const float* qkv_w  = (const float*)d_in[2];
  const float* qkv_b  = (const float*)d_in[3];
  const float* out_w  = (const float*)d_in[4];
  const float* out_b  = (const float*)d_in[5];
  const float* up_w   = (const float*)d_in[6];
  const float* up_b   = (const float*)d_in[7];
  const float* down_w = (const float*)d_in[8];
  const float* down_b = (const float*)d_in[9];
  const float* gamma  = (const float*)d_in[10];
  const float* beta   = (const float*)d_in[11];
  float* logits = (float*)d_out;

  char* ws = (char*)d_ws;
  size_t off = 0;
  auto alloc = [&](size_t b) { char* p = ws + off; off += (b + 255) & ~(size_t)255; return p; };
  u16*   embed_b = (u16*)  alloc((size_t)V_DIM * H_DIM * 2);          // 65.5 MB
  float* hf      = (float*)alloc((size_t)N_TOK * H_DIM * 4);          // 16.8 MB (f32 residual)
  u16*   hb      = (u16*)  alloc((size_t)N_TOK * H_DIM * 2);          //  8.4 MB
  u16*   qkvb    = (u16*)  alloc((size_t)N_TOK * 3 * H_DIM * 2);      // 25.2 MB
  float* scores  = (float*)alloc((size_t)N_BATCH * SEQ * SEQ * 4);    // 33.6 MB
  u16*   attn    = (u16*)  alloc((size_t)N_BATCH * SEQ * SEQ * 2);    // 16.8 MB
  u16*   vT      = (u16*)  alloc((size_t)N_BATCH * H_DIM * SEQ * 2);  //  8.4 MB
  u16*   wqT     = (u16*)  alloc((size_t)3 * H_DIM * H_DIM * 2);
  u16*   woT     = (u16*)  alloc((size_t)H_DIM * H_DIM * 2);
  u16*   wuT     = (u16*)  alloc((size_t)4 * H_DIM * H_DIM * 2);
  u16*   wdT     = (u16*)  alloc((size_t)H_DIM * 4 * H_DIM * 2);
  // time-disjoint aliases (all launches sequential on one stream):
  u16* ab  = qkvb;          // a = attn@v written after last qkv read
  u16* mb  = (u16*)scores;  // mlp hidden written after softmax consumed scores
  u16* hnb = attn;          // layernorm out written after last attn read

  cvt_f32_bf16<<<dim3((V_DIM * H_DIM) / 2048), 256, 0, stream>>>(
      embed, embed_b, (long)V_DIM * H_DIM);
  embed_gather<<<dim3(N_TOK), 256, 0, stream>>>(x, embed, hf, hb);

  for (int l = 0; l < N_LAYER; ++l) {
    const float* qw = qkv_w + (size_t)l * H_DIM * 3 * H_DIM;
    const float* qb = qkv_b + (size_t)l * 3 * H_DIM;
    const float* ow = out_w + (size_t)l * H_DIM * H_DIM;
    const float* ob = out_b + (size_t)l * H_DIM;
    const float* uw = up_w + (size_t)l * H_DIM * 4 * H_DIM;
    const float* ub = up_b + (size_t)l * 4 * H_DIM;
    const float* dw = down_w + (size_t)l * 4 * H_DIM * H_DIM;
    const float* db = down_b + (size_t)l * H_DIM;

    // weight convert+transpose -> [N,K] bf16
    transpose_to_bf16<float><<<dim3(H_DIM / 64, 3 * H_DIM / 64, 1), 256, 0, stream>>>(
        qw, 0, 3 * H_DIM, wqT, 0, H_DIM);
    transpose_to_bf16<float><<<dim3(H_DIM / 64, H_DIM / 64, 1), 256, 0, stream>>>(
        ow, 0, H_DIM, woT, 0, H_DIM);
    transpose_to_bf16<float><<<dim3(H_DIM / 64, 4 * H_DIM / 64, 1), 256, 0, stream>>>(
        uw, 0, 4 * H_DIM, wuT, 0, H_DIM);
    transpose_to_bf16<float><<<dim3(4 * H_DIM / 64, H_DIM / 64, 1), 256, 0, stream>>>(
        dw, 0, H_DIM, wdT, 0, 4 * H_DIM);

    // qkv = h @ qkv_w + b           [4096,3072]
    gemm_nt<EPI_BF16><<<dim3(N_TOK / 128, 3 * H_DIM / 128, 1), 256, 0, stream>>>(
        hb, 0, H_DIM, wqT, 0, H_DIM, qb, 1.f, nullptr, 0, qkvb, 0, 3 * H_DIM, H_DIM);
    // scores = q @ k^T * scale      per batch [2048,2048]
    gemm_nt<EPI_F32S><<<dim3(SEQ / 128, SEQ / 128, N_BATCH), 256, 0, stream>>>(
        qkvb, (long)SEQ * 3 * H_DIM, 3 * H_DIM,
        qkvb + H_DIM, (long)SEQ * 3 * H_DIM, 3 * H_DIM,
        nullptr, 0.03125f, scores, (long)SEQ * SEQ, nullptr, 0, SEQ, H_DIM);
    softmax_rows<<<dim3(N_BATCH * SEQ), 256, 0, stream>>>(scores, attn);
    // vT[h][s] = v[s][h]            per batch [1024,2048]
    transpose_to_bf16<u16><<<dim3(SEQ / 64, H_DIM / 64, N_BATCH), 256, 0, stream>>>(
        qkvb + 2 * H_DIM, (long)SEQ * 3 * H_DIM, 3 * H_DIM, vT, (long)H_DIM * SEQ, SEQ);
    // a = attn @ v                  per batch [2048,1024]
    gemm_nt<EPI_BF16><<<dim3(SEQ / 128, H_DIM / 128, N_BATCH), 256, 0, stream>>>(
        attn, (long)SEQ * SEQ, SEQ, vT, (long)H_DIM * SEQ, SEQ,
        nullptr, 1.f, nullptr, 0, ab, (long)SEQ * H_DIM, H_DIM, SEQ);
    // h += a @ out_w + b            [4096,1024] (f32 residual + bf16 copy)
    gemm_nt<EPI_RES><<<dim3(N_TOK / 128, H_DIM / 128, 1), 256, 0, stream>>>(
        ab, 0, H_DIM, woT, 0, H_DIM, ob, 1.f, hf, 0, hb, 0, H_DIM, H_DIM);
    // m = relu(h @ up_w + b)        [4096,4096]
    gemm_nt<EPI_RELU><<<dim3(N_TOK / 128, 4 * H_DIM / 128, 1), 256, 0, stream>>>(
        hb, 0, H_DIM, wuT, 0, H_DIM, ub, 1.f, nullptr, 0, mb, 0, 4 * H_DIM, H_DIM);
    // h += m @ down_w + b           [4096,1024]
    gemm_nt<EPI_RES><<<dim3(N_TOK / 128, H_DIM / 128, 1), 256, 0, stream>>>(
        mb, 0, 4 * H_DIM, wdT, 0, 4 * H_DIM, db, 1.f, hf, 0, hb, 0, H_DIM, 4 * H_DIM);
  }

  layernorm_rows<<<dim3(N_TOK), 256, 0, stream>>>(hf, gamma, beta, hnb);
  // logits = hn @ embed^T           [4096,32000]
  gemm_nt<EPI_F32S><<<dim3(N_TOK / 128, V_DIM / 128, 1), 256, 0, stream>>>(
      hnb, 0, H_DIM, embed_b, 0, H_DIM, nullptr, 1.f, logits, 0, nullptr, 0, V_DIM, H_DIM);
}